// Round 11
// baseline (1742.418 us; speedup 1.0000x reference)
//
#include <hip/hip_runtime.h>
#include <hip/hip_bf16.h>
#include <math.h>

#define BSHIFT 7                 // 128 nodes per bucket
#define NBUCK(N) (((N) + 127) >> 7)
#define TILE 8192                // edges per partition block
#define CAP 5632                 // max edges/bucket (mean 4220, sd ~64 -> ~22 sigma)

typedef short bf16x8 __attribute__((ext_vector_type(8)));
typedef float f32x16 __attribute__((ext_vector_type(16)));

// ---- bf16 helpers ---------------------------------------------------------
__device__ __forceinline__ unsigned short f2bf(float f) {
    unsigned u = __float_as_uint(f);
    u += 0x7fffu + ((u >> 16) & 1u);      // RNE
    return (unsigned short)(u >> 16);
}
__device__ __forceinline__ unsigned packbf2(float lo, float hi) {
    return (unsigned)f2bf(lo) | ((unsigned)f2bf(hi) << 16);
}
__device__ __forceinline__ float bf_lo(unsigned u) { return __uint_as_float(u << 16); }
__device__ __forceinline__ float bf_hi(unsigned u) { return __uint_as_float(u & 0xffff0000u); }

// ---- partition: edges -> fixed-stride dst-buckets & src-buckets -----------
// Direct global scatter (72 us measured form, r8) + fused per-block
// reservation (no bcount/bscan). Write amplification accepted: BW is not
// the binding constraint (26% peak measured); staging variants were slower.
__global__ __launch_bounds__(256) void part_kernel(
    const int* __restrict__ src, const int* __restrict__ dst,
    int* __restrict__ gcurD, int* __restrict__ gcurS,
    int* __restrict__ gbufD, unsigned char* __restrict__ gbufS, int E, int K) {
    __shared__ int cD[800], bD[800], cS[800], bS[800];   // 12.8 KB
    const int t = threadIdx.x;
    const int tile = blockIdx.x * TILE;
    for (int i = t; i < K; i += 256) { cD[i] = 0; cS[i] = 0; }
    __syncthreads();

    int dv[32];
    #pragma unroll
    for (int i = 0; i < 32; ++i) {
        const int e = tile + i * 256 + t;
        dv[i] = (e < E) ? dst[e] : -1;
        if (dv[i] >= 0) {
            atomicAdd(&cD[dv[i] >> BSHIFT], 1);
            atomicAdd(&cS[src[e] >> BSHIFT], 1);
        }
    }
    __syncthreads();
    for (int i = t; i < K; i += 256) {
        int c = cD[i];
        bD[i] = (c ? atomicAdd(&gcurD[i], c) : 0) + i * CAP;
        cD[i] = 0;
        c = cS[i];
        bS[i] = (c ? atomicAdd(&gcurS[i], c) : 0) + i * CAP;
        cS[i] = 0;
    }
    __syncthreads();
    #pragma unroll
    for (int i = 0; i < 32; ++i) {
        if (dv[i] >= 0) {
            const int e = tile + i * 256 + t;
            const int sv = src[e];
            const int b1 = dv[i] >> BSHIFT;
            const int p1 = bD[b1] + atomicAdd(&cD[b1], 1);
            gbufD[p1] = ((dv[i] & 127) << 17) | sv;
            const int b2 = sv >> BSHIFT;
            const int p2 = bS[b2] + atomicAdd(&cS[b2], 1);
            gbufS[p2] = (unsigned char)(sv & 127);
        }
    }
}

// ---- fillS: per src-bucket (128 nodes): outdeg -> nsrc --------------------
__global__ __launch_bounds__(256) void fillS_kernel(
    const int* __restrict__ cntS, const unsigned char* __restrict__ gbufS,
    float* __restrict__ nsrc, int N, int K) {
    __shared__ int cnt[128];
    const int t = threadIdx.x;
    const int b = blockIdx.x;
    if (t < 128) cnt[t] = 0;
    __syncthreads();
    const int bs = b * CAP;
    const int be = bs + cntS[b];
    for (int idx = bs + t; idx < be; idx += 256)
        atomicAdd(&cnt[gbufS[idx]], 1);
    __syncthreads();
    const int n = (b << BSHIFT) + t;
    if (t < 128 && n < N) nsrc[n] = rsqrtf((float)cnt[t]);   // self-loops => deg>=1
}

// ---- GEMM1 (MFMA): h1[n][j] = bf16( nsrc[n] * sum_k feat[n][k]*W1[k][j] ) -
__global__ __launch_bounds__(256) void gemm1_kernel(
    const float* __restrict__ feat, const float* __restrict__ W1,
    const float* __restrict__ nsrc, unsigned short* __restrict__ h1, int N) {
    __shared__ short W1t[32 * 264];    // 16.9 KB: W1t[c][k] = bf16(W1[k][c])
    const int t = threadIdx.x;
    for (int i = t; i < 8192; i += 256) {
        const int k = i >> 5, c = i & 31;
        W1t[c * 264 + k] = (short)f2bf(W1[i]);
    }
    __syncthreads();

    const int l  = t & 63;
    const int wv = t >> 6;
    const int base = blockIdx.x * 128 + wv * 32;
    const int m  = l & 31;
    const int kh = (l >> 5) << 3;
    int r = base + m;
    if (r >= N) r = N - 1;
    const float* fr = feat + (size_t)r * 256 + kh;
    const short* wr = &W1t[m * 264 + kh];

    f32x16 acc;
    #pragma unroll
    for (int i = 0; i < 16; ++i) acc[i] = 0.f;

    #pragma unroll
    for (int kb = 0; kb < 16; ++kb) {
        const float4 f0 = *(const float4*)(fr + kb * 16);
        const float4 f1 = *(const float4*)(fr + kb * 16 + 4);
        bf16x8 a;
        a[0] = (short)f2bf(f0.x); a[1] = (short)f2bf(f0.y);
        a[2] = (short)f2bf(f0.z); a[3] = (short)f2bf(f0.w);
        a[4] = (short)f2bf(f1.x); a[5] = (short)f2bf(f1.y);
        a[6] = (short)f2bf(f1.z); a[7] = (short)f2bf(f1.w);
        const bf16x8 b = *(const bf16x8*)(wr + kb * 16);
        acc = __builtin_amdgcn_mfma_f32_32x32x16_bf16(a, b, acc, 0, 0, 0);
    }

    const int rbase = base + ((l >> 5) << 2);
    #pragma unroll
    for (int reg = 0; reg < 16; ++reg) {
        const int row = rbase + (reg & 3) + ((reg >> 2) << 3);
        if (row < N)
            h1[(size_t)row * 32 + m] = f2bf(acc[reg] * nsrc[row]);
    }
}

// ---- agg1 (bucket-direct): LDS fp32 acc; computes indeg -> ndst; ----------
// x1s[n] = bf16( relu(ndst*sum h1[src] + b1) * nsrc ). One block per bucket.
// acc bank rotation (f+ld)&31 spreads ds_add_f32 across banks.
__global__ __launch_bounds__(256) void agg1_kernel(
    const int* __restrict__ cntD, const int* __restrict__ gbufD,
    const unsigned* __restrict__ h1, const float* __restrict__ nsrc,
    const float* __restrict__ b1, float* __restrict__ ndst,
    unsigned* __restrict__ x1s, int N, int K) {
    __shared__ float acc[128 * 32];   // 16 KB
    __shared__ int cnt[128];
    const int t = threadIdx.x;
    const int b = blockIdx.x;
    for (int i = t; i < 4096; i += 256) acc[i] = 0.f;
    if (t < 128) cnt[t] = 0;
    __syncthreads();
    const int bs = b * CAP;
    const int be = bs + cntD[b];
    const int g = t >> 2, c = t & 3;
    const int f0 = c << 3;
    const uint4* H = (const uint4*)h1;

    int idx = bs + g;
    for (; idx + 64 < be; idx += 128) {       // unroll 2: two gathers in flight
        const int p0 = gbufD[idx];
        const int p1 = gbufD[idx + 64];
        const int ld0 = p0 >> 17, ld1 = p1 >> 17;
        const uint4 q0 = H[(size_t)(p0 & 131071) * 4 + c];
        const uint4 q1 = H[(size_t)(p1 & 131071) * 4 + c];
        if (c == 0) { atomicAdd(&cnt[ld0], 1); atomicAdd(&cnt[ld1], 1); }
        float* a0 = &acc[ld0 << 5];
        unsafeAtomicAdd(&a0[(f0 + 0 + ld0) & 31], bf_lo(q0.x));
        unsafeAtomicAdd(&a0[(f0 + 1 + ld0) & 31], bf_hi(q0.x));
        unsafeAtomicAdd(&a0[(f0 + 2 + ld0) & 31], bf_lo(q0.y));
        unsafeAtomicAdd(&a0[(f0 + 3 + ld0) & 31], bf_hi(q0.y));
        unsafeAtomicAdd(&a0[(f0 + 4 + ld0) & 31], bf_lo(q0.z));
        unsafeAtomicAdd(&a0[(f0 + 5 + ld0) & 31], bf_hi(q0.z));
        unsafeAtomicAdd(&a0[(f0 + 6 + ld0) & 31], bf_lo(q0.w));
        unsafeAtomicAdd(&a0[(f0 + 7 + ld0) & 31], bf_hi(q0.w));
        float* a1 = &acc[ld1 << 5];
        unsafeAtomicAdd(&a1[(f0 + 0 + ld1) & 31], bf_lo(q1.x));
        unsafeAtomicAdd(&a1[(f0 + 1 + ld1) & 31], bf_hi(q1.x));
        unsafeAtomicAdd(&a1[(f0 + 2 + ld1) & 31], bf_lo(q1.y));
        unsafeAtomicAdd(&a1[(f0 + 3 + ld1) & 31], bf_hi(q1.y));
        unsafeAtomicAdd(&a1[(f0 + 4 + ld1) & 31], bf_lo(q1.z));
        unsafeAtomicAdd(&a1[(f0 + 5 + ld1) & 31], bf_hi(q1.z));
        unsafeAtomicAdd(&a1[(f0 + 6 + ld1) & 31], bf_lo(q1.w));
        unsafeAtomicAdd(&a1[(f0 + 7 + ld1) & 31], bf_hi(q1.w));
    }
    if (idx < be) {
        const int p0 = gbufD[idx];
        const int ld0 = p0 >> 17;
        const uint4 q0 = H[(size_t)(p0 & 131071) * 4 + c];
        if (c == 0) atomicAdd(&cnt[ld0], 1);
        float* a0 = &acc[ld0 << 5];
        unsafeAtomicAdd(&a0[(f0 + 0 + ld0) & 31], bf_lo(q0.x));
        unsafeAtomicAdd(&a0[(f0 + 1 + ld0) & 31], bf_hi(q0.x));
        unsafeAtomicAdd(&a0[(f0 + 2 + ld0) & 31], bf_lo(q0.y));
        unsafeAtomicAdd(&a0[(f0 + 3 + ld0) & 31], bf_hi(q0.y));
        unsafeAtomicAdd(&a0[(f0 + 4 + ld0) & 31], bf_lo(q0.z));
        unsafeAtomicAdd(&a0[(f0 + 5 + ld0) & 31], bf_hi(q0.z));
        unsafeAtomicAdd(&a0[(f0 + 6 + ld0) & 31], bf_lo(q0.w));
        unsafeAtomicAdd(&a0[(f0 + 7 + ld0) & 31], bf_hi(q0.w));
    }
    __syncthreads();

    if (t < 128) {
        const int n = (b << BSHIFT) + t;
        if (n < N) {
            const float nd = rsqrtf((float)cnt[t]);
            ndst[n] = nd;
            const float ns = nsrc[n];
            const float* a = &acc[t << 5];
            unsigned o[16];
            #pragma unroll
            for (int f = 0; f < 32; f += 2) {
                const float v0 = fmaxf(a[(f + t) & 31] * nd + b1[f], 0.f) * ns;
                const float v1 = fmaxf(a[(f + 1 + t) & 31] * nd + b1[f + 1], 0.f) * ns;
                o[f >> 1] = packbf2(v0, v1);
            }
            uint4* X = (uint4*)x1s + (size_t)n * 4;
            X[0] = make_uint4(o[0], o[1], o[2], o[3]);
            X[1] = make_uint4(o[4], o[5], o[6], o[7]);
            X[2] = make_uint4(o[8], o[9], o[10], o[11]);
            X[3] = make_uint4(o[12], o[13], o[14], o[15]);
        }
    }
}

// ---- agg2 (bucket-direct): a2[n] = ndst[n] * sum x1s[src], fp32 out -------
__global__ __launch_bounds__(256) void agg2_kernel(
    const int* __restrict__ cntD, const int* __restrict__ gbufD,
    const unsigned* __restrict__ x1s, const float* __restrict__ ndst,
    float* __restrict__ a2out, int N, int K) {
    __shared__ float acc[128 * 32];   // 16 KB
    const int t = threadIdx.x;
    const int b = blockIdx.x;
    for (int i = t; i < 4096; i += 256) acc[i] = 0.f;
    __syncthreads();
    const int bs = b * CAP;
    const int be = bs + cntD[b];
    const int g = t >> 2, c = t & 3;
    const int f0 = c << 3;
    const uint4* H = (const uint4*)x1s;

    int idx = bs + g;
    for (; idx + 64 < be; idx += 128) {
        const int p0 = gbufD[idx];
        const int p1 = gbufD[idx + 64];
        const int ld0 = p0 >> 17, ld1 = p1 >> 17;
        const uint4 q0 = H[(size_t)(p0 & 131071) * 4 + c];
        const uint4 q1 = H[(size_t)(p1 & 131071) * 4 + c];
        float* a0 = &acc[ld0 << 5];
        unsafeAtomicAdd(&a0[(f0 + 0 + ld0) & 31], bf_lo(q0.x));
        unsafeAtomicAdd(&a0[(f0 + 1 + ld0) & 31], bf_hi(q0.x));
        unsafeAtomicAdd(&a0[(f0 + 2 + ld0) & 31], bf_lo(q0.y));
        unsafeAtomicAdd(&a0[(f0 + 3 + ld0) & 31], bf_hi(q0.y));
        unsafeAtomicAdd(&a0[(f0 + 4 + ld0) & 31], bf_lo(q0.z));
        unsafeAtomicAdd(&a0[(f0 + 5 + ld0) & 31], bf_hi(q0.z));
        unsafeAtomicAdd(&a0[(f0 + 6 + ld0) & 31], bf_lo(q0.w));
        unsafeAtomicAdd(&a0[(f0 + 7 + ld0) & 31], bf_hi(q0.w));
        float* a1 = &acc[ld1 << 5];
        unsafeAtomicAdd(&a1[(f0 + 0 + ld1) & 31], bf_lo(q1.x));
        unsafeAtomicAdd(&a1[(f0 + 1 + ld1) & 31], bf_hi(q1.x));
        unsafeAtomicAdd(&a1[(f0 + 2 + ld1) & 31], bf_lo(q1.y));
        unsafeAtomicAdd(&a1[(f0 + 3 + ld1) & 31], bf_hi(q1.y));
        unsafeAtomicAdd(&a1[(f0 + 4 + ld1) & 31], bf_lo(q1.z));
        unsafeAtomicAdd(&a1[(f0 + 5 + ld1) & 31], bf_hi(q1.z));
        unsafeAtomicAdd(&a1[(f0 + 6 + ld1) & 31], bf_lo(q1.w));
        unsafeAtomicAdd(&a1[(f0 + 7 + ld1) & 31], bf_hi(q1.w));
    }
    if (idx < be) {
        const int p0 = gbufD[idx];
        const int ld0 = p0 >> 17;
        const uint4 q0 = H[(size_t)(p0 & 131071) * 4 + c];
        float* a0 = &acc[ld0 << 5];
        unsafeAtomicAdd(&a0[(f0 + 0 + ld0) & 31], bf_lo(q0.x));
        unsafeAtomicAdd(&a0[(f0 + 1 + ld0) & 31], bf_hi(q0.x));
        unsafeAtomicAdd(&a0[(f0 + 2 + ld0) & 31], bf_lo(q0.y));
        unsafeAtomicAdd(&a0[(f0 + 3 + ld0) & 31], bf_hi(q0.y));
        unsafeAtomicAdd(&a0[(f0 + 4 + ld0) & 31], bf_lo(q0.z));
        unsafeAtomicAdd(&a0[(f0 + 5 + ld0) & 31], bf_hi(q0.z));
        unsafeAtomicAdd(&a0[(f0 + 6 + ld0) & 31], bf_lo(q0.w));
        unsafeAtomicAdd(&a0[(f0 + 7 + ld0) & 31], bf_hi(q0.w));
    }
    __syncthreads();

    if (t < 128) {
        const int n = (b << BSHIFT) + t;
        if (n < N) {
            const float nd = ndst[n];
            const float* a = &acc[t << 5];
            float* O = a2out + (size_t)n * 32;
            #pragma unroll
            for (int f = 0; f < 32; f += 4) {
                float4 v;
                v.x = a[(f + 0 + t) & 31] * nd;
                v.y = a[(f + 1 + t) & 31] * nd;
                v.z = a[(f + 2 + t) & 31] * nd;
                v.w = a[(f + 3 + t) & 31] * nd;
                *(float4*)(O + f) = v;
            }
        }
    }
}

// ---- final: out = log_softmax(a2 @ W2 + b2), one wave per node ------------
__global__ __launch_bounds__(256) void final_kernel(
    const float* __restrict__ a2, const float* __restrict__ W2,
    const float* __restrict__ b2, float* __restrict__ out, int N) {
    __shared__ float sW2[32 * 40];
    __shared__ float sb2[40];
    const int t = threadIdx.x;
    for (int i = t; i < 1280; i += 256) sW2[i] = W2[i];
    if (t < 40) sb2[t] = b2[t];
    __syncthreads();
    const int lane = t & 63;
    const int n = blockIdx.x * 4 + (t >> 6);
    if (n >= N) return;
    const float v = a2[(size_t)n * 32 + (lane & 31)];
    const int jj = (lane < 40) ? lane : 39;
    float z = sb2[jj];
    #pragma unroll
    for (int k = 0; k < 32; ++k) {
        const float ak = __shfl(v, k, 64);
        z += ak * sW2[k * 40 + jj];
    }
    if (lane >= 40) z = -INFINITY;
    float m = z;
    #pragma unroll
    for (int off = 32; off; off >>= 1) m = fmaxf(m, __shfl_xor(m, off, 64));
    float e = (lane < 40) ? __expf(z - m) : 0.f;
    float s = e;
    #pragma unroll
    for (int off = 32; off; off >>= 1) s += __shfl_xor(s, off, 64);
    if (lane < 40) out[(size_t)n * 40 + lane] = z - m - __logf(s);
}

extern "C" void kernel_launch(void* const* d_in, const int* in_sizes, int n_in,
                              void* d_out, int out_size, void* d_ws, size_t ws_size,
                              hipStream_t stream) {
    const float* feat = (const float*)d_in[0];
    const int*   src  = (const int*)d_in[1];
    const int*   dst  = (const int*)d_in[2];
    const float* W1   = (const float*)d_in[3];
    const float* b1   = (const float*)d_in[4];
    const float* W2   = (const float*)d_in[5];
    const float* b2   = (const float*)d_in[6];
    float* out = (float*)d_out;

    const int N = in_sizes[0] / 256;   // 100000
    const int E = in_sizes[1];         // 3300000
    const int K = NBUCK(N);            // 782 buckets of 128 nodes

    // layout (no CSR; gbufD/gbufS persist through the aggs): ~48.4 MB
    char* p = (char*)d_ws;
    float* nsrc = (float*)p;                 p += (size_t)N * 4;        // 400 KB
    float* ndst = (float*)p;                 p += (size_t)N * 4;
    unsigned* h1  = (unsigned*)p;            p += (size_t)N * 64;       // 6.4 MB
    unsigned* x1s = (unsigned*)p;            p += (size_t)N * 64;       // 6.4 MB
    float* a2 = (float*)p;                   p += (size_t)N * 128;      // 12.8 MB
    int* gcurD    = (int*)p;                 p += 800 * 4;
    int* gcurS    = (int*)p;                 p += 800 * 4;
    int* gbufD    = (int*)p;                 p += (size_t)K * CAP * 4;  // 17.6 MB
    unsigned char* gbufS = (unsigned char*)p; p += (size_t)K * CAP;     // 4.4 MB

    hipMemsetAsync(gcurD, 0, sizeof(int) * 1600, stream);  // gcurD + gcurS

    const int PB = (E + TILE - 1) / TILE;

    part_kernel<<<PB, 256, 0, stream>>>(src, dst, gcurD, gcurS, gbufD, gbufS, E, K);
    fillS_kernel<<<K, 256, 0, stream>>>(gcurS, gbufS, nsrc, N, K);

    gemm1_kernel<<<(N + 127) / 128, 256, 0, stream>>>(feat, W1, nsrc, (unsigned short*)h1, N);
    agg1_kernel<<<K, 256, 0, stream>>>(gcurD, gbufD, h1, nsrc, b1, ndst, x1s, N, K);
    agg2_kernel<<<K, 256, 0, stream>>>(gcurD, gbufD, x1s, ndst, a2, N, K);
    final_kernel<<<(N + 3) / 4, 256, 0, stream>>>(a2, W2, b2, out, N);
}

// Round 12
// 483.960 us; speedup vs baseline: 3.6003x; 3.6003x over previous
//
#include <hip/hip_runtime.h>
#include <hip/hip_bf16.h>
#include <math.h>

#define BSHIFT 7                 // 128 nodes per bucket
#define NBUCK(N) (((N) + 127) >> 7)
#define TILE 8192                // edges per partition block
#define CAP 5632                 // max edges/bucket (mean 4224, sd ~65 -> ~21 sigma)

typedef short bf16x8 __attribute__((ext_vector_type(8)));
typedef float f32x16 __attribute__((ext_vector_type(16)));

// ---- bf16 helpers ---------------------------------------------------------
__device__ __forceinline__ unsigned short f2bf(float f) {
    unsigned u = __float_as_uint(f);
    u += 0x7fffu + ((u >> 16) & 1u);      // RNE
    return (unsigned short)(u >> 16);
}
__device__ __forceinline__ unsigned packbf2(float lo, float hi) {
    return (unsigned)f2bf(lo) | ((unsigned)f2bf(hi) << 16);
}
__device__ __forceinline__ float bf_lo(unsigned u) { return __uint_as_float(u << 16); }
__device__ __forceinline__ float bf_hi(unsigned u) { return __uint_as_float(u & 0xffff0000u); }

// ---- partition: edges -> fixed-stride dst-buckets & src-buckets -----------
// Direct global scatter (r8's measured-fast form) + fused per-block
// reservation (no bcount/bscan). Write amplification accepted: atomics/BW
// were not binding (26% peak measured); LDS-staged variants were slower.
__global__ __launch_bounds__(256) void part_kernel(
    const int* __restrict__ src, const int* __restrict__ dst,
    int* __restrict__ gcurD, int* __restrict__ gcurS,
    int* __restrict__ gbufD, unsigned char* __restrict__ gbufS, int E, int K) {
    __shared__ int cD[800], bD[800], cS[800], bS[800];   // 12.8 KB
    const int t = threadIdx.x;
    const int tile = blockIdx.x * TILE;
    for (int i = t; i < K; i += 256) { cD[i] = 0; cS[i] = 0; }
    __syncthreads();

    int dv[32];
    #pragma unroll
    for (int i = 0; i < 32; ++i) {
        const int e = tile + i * 256 + t;
        dv[i] = (e < E) ? dst[e] : -1;
        if (dv[i] >= 0) {
            atomicAdd(&cD[dv[i] >> BSHIFT], 1);
            atomicAdd(&cS[src[e] >> BSHIFT], 1);
        }
    }
    __syncthreads();
    for (int i = t; i < K; i += 256) {
        int c = cD[i];
        bD[i] = (c ? atomicAdd(&gcurD[i], c) : 0) + i * CAP;
        cD[i] = 0;
        c = cS[i];
        bS[i] = (c ? atomicAdd(&gcurS[i], c) : 0) + i * CAP;
        cS[i] = 0;
    }
    __syncthreads();
    #pragma unroll
    for (int i = 0; i < 32; ++i) {
        if (dv[i] >= 0) {
            const int e = tile + i * 256 + t;
            const int sv = src[e];
            const int b1 = dv[i] >> BSHIFT;
            const int p1 = bD[b1] + atomicAdd(&cD[b1], 1);
            gbufD[p1] = ((dv[i] & 127) << 17) | sv;
            const int b2 = sv >> BSHIFT;
            const int p2 = bS[b2] + atomicAdd(&cS[b2], 1);
            gbufS[p2] = (unsigned char)(sv & 127);
        }
    }
}

// ---- fillS: per src-bucket (128 nodes): outdeg -> nsrc --------------------
__global__ __launch_bounds__(256) void fillS_kernel(
    const int* __restrict__ cntS, const unsigned char* __restrict__ gbufS,
    float* __restrict__ nsrc, int N, int K) {
    __shared__ int cnt[128];
    const int t = threadIdx.x;
    const int b = blockIdx.x;
    if (t < 128) cnt[t] = 0;
    __syncthreads();
    const int bs = b * CAP;
    const int be = bs + cntS[b];
    for (int idx = bs + t; idx < be; idx += 256)
        atomicAdd(&cnt[gbufS[idx]], 1);
    __syncthreads();
    const int n = (b << BSHIFT) + t;
    if (t < 128 && n < N) nsrc[n] = rsqrtf((float)cnt[t]);   // self-loops => deg>=1
}

// ---- fillD: per dst-bucket (128 nodes): indeg, rowstart, ndst, CSR --------
// Scattered csr writes confined to this block's 22 KB window -> full-line
// merges in one XCD L2.
__global__ __launch_bounds__(256) void fillD_kernel(
    const int* __restrict__ cntD, const int* __restrict__ gbufD,
    int* __restrict__ csr_src, int* __restrict__ rowstart, int* __restrict__ indeg,
    float* __restrict__ ndst, int N, int K) {
    __shared__ int cnt[128];
    __shared__ int sc[128];
    __shared__ int cur[128];
    const int t = threadIdx.x;
    const int b = blockIdx.x;
    if (t < 128) cnt[t] = 0;
    __syncthreads();
    const int bs = b * CAP;
    const int be = bs + cntD[b];
    for (int idx = bs + t; idx < be; idx += 256)
        atomicAdd(&cnt[gbufD[idx] >> 17], 1);
    __syncthreads();
    if (t < 128) sc[t] = cnt[t];
    __syncthreads();
    for (int off = 1; off < 128; off <<= 1) {
        int x = (t < 128 && t >= off) ? sc[t - off] : 0;
        __syncthreads();
        if (t < 128) sc[t] += x;
        __syncthreads();
    }
    if (t < 128) {
        const int deg = cnt[t];
        const int rs = bs + sc[t] - deg;
        cur[t] = rs;
        const int n = (b << BSHIFT) + t;
        if (n < N) {
            rowstart[n] = rs;
            indeg[n] = deg;
            ndst[n] = rsqrtf((float)deg);   // self-loops => deg >= 1
        }
    }
    __syncthreads();
    for (int idx = bs + t; idx < be; idx += 256) {
        const int p = gbufD[idx];
        const int pos = atomicAdd(&cur[p >> 17], 1);
        csr_src[pos] = p & 131071;
    }
}

// ---- GEMM1 (MFMA): h1[n][j] = bf16( nsrc[n] * sum_k feat[n][k]*W1[k][j] ) -
__global__ __launch_bounds__(256) void gemm1_kernel(
    const float* __restrict__ feat, const float* __restrict__ W1,
    const float* __restrict__ nsrc, unsigned short* __restrict__ h1, int N) {
    __shared__ short W1t[32 * 264];    // 16.9 KB: W1t[c][k] = bf16(W1[k][c])
    const int t = threadIdx.x;
    for (int i = t; i < 8192; i += 256) {
        const int k = i >> 5, c = i & 31;
        W1t[c * 264 + k] = (short)f2bf(W1[i]);
    }
    __syncthreads();

    const int l  = t & 63;
    const int wv = t >> 6;
    const int base = blockIdx.x * 128 + wv * 32;
    const int m  = l & 31;
    const int kh = (l >> 5) << 3;
    int r = base + m;
    if (r >= N) r = N - 1;
    const float* fr = feat + (size_t)r * 256 + kh;
    const short* wr = &W1t[m * 264 + kh];

    f32x16 acc;
    #pragma unroll
    for (int i = 0; i < 16; ++i) acc[i] = 0.f;

    #pragma unroll
    for (int kb = 0; kb < 16; ++kb) {
        const float4 f0 = *(const float4*)(fr + kb * 16);
        const float4 f1 = *(const float4*)(fr + kb * 16 + 4);
        bf16x8 a;
        a[0] = (short)f2bf(f0.x); a[1] = (short)f2bf(f0.y);
        a[2] = (short)f2bf(f0.z); a[3] = (short)f2bf(f0.w);
        a[4] = (short)f2bf(f1.x); a[5] = (short)f2bf(f1.y);
        a[6] = (short)f2bf(f1.z); a[7] = (short)f2bf(f1.w);
        const bf16x8 b = *(const bf16x8*)(wr + kb * 16);
        acc = __builtin_amdgcn_mfma_f32_32x32x16_bf16(a, b, acc, 0, 0, 0);
    }

    const int rbase = base + ((l >> 5) << 2);
    #pragma unroll
    for (int reg = 0; reg < 16; ++reg) {
        const int row = rbase + (reg & 3) + ((reg >> 2) << 3);
        if (row < N)
            h1[(size_t)row * 32 + m] = f2bf(acc[reg] * nsrc[row]);
    }
}

// ---- agg1: x1s[n] = bf16( relu(ndst[n]*sum h1[src] + b1) * nsrc[n] ) ------
// 64 nodes/block, 4 lanes/node, register accumulation (the measured-fast form).
__global__ __launch_bounds__(256) void agg1_kernel(
    const int* __restrict__ csr_src, const int* __restrict__ rowstart,
    const int* __restrict__ indeg, const unsigned* __restrict__ h1,
    const float* __restrict__ ndst, const float* __restrict__ nsrc,
    const float* __restrict__ b1, unsigned* __restrict__ x1s, int N) {
    const int t = threadIdx.x;
    const int n = blockIdx.x * 64 + (t >> 2);
    if (n >= N) return;
    const int c = t & 3;
    const int rs = rowstart[n];
    const int re = rs + indeg[n];
    float a0=0.f,a1=0.f,a2=0.f,a3=0.f,a4=0.f,a5=0.f,a6=0.f,a7=0.f;
    const uint4* H = (const uint4*)h1;
    for (int k = rs; k < re; ++k) {
        const int s = csr_src[k];
        const uint4 q = H[(size_t)s * 4 + c];
        a0 += bf_lo(q.x); a1 += bf_hi(q.x);
        a2 += bf_lo(q.y); a3 += bf_hi(q.y);
        a4 += bf_lo(q.z); a5 += bf_hi(q.z);
        a6 += bf_lo(q.w); a7 += bf_hi(q.w);
    }
    const float nd = ndst[n];
    const float ns = nsrc[n];
    const float* bb = b1 + c * 8;
    float x0 = fmaxf(a0 * nd + bb[0], 0.f) * ns;
    float x1 = fmaxf(a1 * nd + bb[1], 0.f) * ns;
    float x2 = fmaxf(a2 * nd + bb[2], 0.f) * ns;
    float x3 = fmaxf(a3 * nd + bb[3], 0.f) * ns;
    float x4 = fmaxf(a4 * nd + bb[4], 0.f) * ns;
    float x5 = fmaxf(a5 * nd + bb[5], 0.f) * ns;
    float x6 = fmaxf(a6 * nd + bb[6], 0.f) * ns;
    float x7 = fmaxf(a7 * nd + bb[7], 0.f) * ns;
    uint4 o;
    o.x = packbf2(x0, x1); o.y = packbf2(x2, x3);
    o.z = packbf2(x4, x5); o.w = packbf2(x6, x7);
    ((uint4*)x1s)[(size_t)n * 4 + c] = o;
}

// ---- agg2: a2[n] = ndst[n] * sum x1s[src]   (fp32 out, 32-wide) -----------
__global__ __launch_bounds__(256) void agg2_kernel(
    const int* __restrict__ csr_src, const int* __restrict__ rowstart,
    const int* __restrict__ indeg, const unsigned* __restrict__ x1s,
    const float* __restrict__ ndst, float* __restrict__ a2out, int N) {
    const int t = threadIdx.x;
    const int n = blockIdx.x * 64 + (t >> 2);
    if (n >= N) return;
    const int c = t & 3;
    const int rs = rowstart[n];
    const int re = rs + indeg[n];
    float a0=0.f,a1=0.f,a2=0.f,a3=0.f,a4=0.f,a5=0.f,a6=0.f,a7=0.f;
    const uint4* H = (const uint4*)x1s;
    for (int k = rs; k < re; ++k) {
        const int s = csr_src[k];
        const uint4 q = H[(size_t)s * 4 + c];
        a0 += bf_lo(q.x); a1 += bf_hi(q.x);
        a2 += bf_lo(q.y); a3 += bf_hi(q.y);
        a4 += bf_lo(q.z); a5 += bf_hi(q.z);
        a6 += bf_lo(q.w); a7 += bf_hi(q.w);
    }
    const float nd = ndst[n];
    float4 o0 = {a0 * nd, a1 * nd, a2 * nd, a3 * nd};
    float4 o1 = {a4 * nd, a5 * nd, a6 * nd, a7 * nd};
    *(float4*)&a2out[(size_t)n * 32 + c * 8] = o0;
    *(float4*)&a2out[(size_t)n * 32 + c * 8 + 4] = o1;
}

// ---- final: out = log_softmax(a2 @ W2 + b2), one wave per node ------------
__global__ __launch_bounds__(256) void final_kernel(
    const float* __restrict__ a2, const float* __restrict__ W2,
    const float* __restrict__ b2, float* __restrict__ out, int N) {
    __shared__ float sW2[32 * 40];
    __shared__ float sb2[40];
    const int t = threadIdx.x;
    for (int i = t; i < 1280; i += 256) sW2[i] = W2[i];
    if (t < 40) sb2[t] = b2[t];
    __syncthreads();
    const int lane = t & 63;
    const int n = blockIdx.x * 4 + (t >> 6);
    if (n >= N) return;
    const float v = a2[(size_t)n * 32 + (lane & 31)];
    const int jj = (lane < 40) ? lane : 39;
    float z = sb2[jj];
    #pragma unroll
    for (int k = 0; k < 32; ++k) {
        const float ak = __shfl(v, k, 64);
        z += ak * sW2[k * 40 + jj];
    }
    if (lane >= 40) z = -INFINITY;
    float m = z;
    #pragma unroll
    for (int off = 32; off; off >>= 1) m = fmaxf(m, __shfl_xor(m, off, 64));
    float e = (lane < 40) ? __expf(z - m) : 0.f;
    float s = e;
    #pragma unroll
    for (int off = 32; off; off >>= 1) s += __shfl_xor(s, off, 64);
    if (lane < 40) out[(size_t)n * 40 + lane] = z - m - __logf(s);
}

extern "C" void kernel_launch(void* const* d_in, const int* in_sizes, int n_in,
                              void* d_out, int out_size, void* d_ws, size_t ws_size,
                              hipStream_t stream) {
    const float* feat = (const float*)d_in[0];
    const int*   src  = (const int*)d_in[1];
    const int*   dst  = (const int*)d_in[2];
    const float* W1   = (const float*)d_in[3];
    const float* b1   = (const float*)d_in[4];
    const float* W2   = (const float*)d_in[5];
    const float* b2   = (const float*)d_in[6];
    float* out = (float*)d_out;

    const int N = in_sizes[0] / 256;   // 100000
    const int E = in_sizes[1];         // 3300000
    const int K = NBUCK(N);            // 782 buckets of 128 nodes

    // layout: nsrc/ndst fp32, h1/x1s bf16 (64 B rows), a2 fp32, CSR.  ~45 MB
    char* p = (char*)d_ws;
    float* nsrc = (float*)p;                 p += (size_t)N * 4;        // 400 KB
    float* ndst = (float*)p;                 p += (size_t)N * 4;
    unsigned* h1  = (unsigned*)p;            p += (size_t)N * 64;       // 6.4 MB
    unsigned* x1s = (unsigned*)p;            p += (size_t)N * 64;       // 6.4 MB
    float* a2 = (float*)p;                   p += (size_t)N * 128;      // 12.8 MB
    int* rowstart = (int*)p;                 p += (size_t)N * 4;
    int* indeg_i  = (int*)p;                 p += (size_t)N * 4;
    int* gcurD    = (int*)p;                 p += 800 * 4;
    int* gcurS    = (int*)p;                 p += 800 * 4;
    int* csr_src  = (int*)p;                 p += (size_t)K * CAP * 4;  // 17.6 MB
    // transient overlays over [h1, x1s, a2] (25.6 MB dead during CSR build):
    int* gbufD = (int*)h1;                                  // K*CAP ints = 17.6 MB
    unsigned char* gbufS = (unsigned char*)h1 + (size_t)K * CAP * 4;  // 4.4 MB

    hipMemsetAsync(gcurD, 0, sizeof(int) * 1600, stream);  // gcurD + gcurS

    const int PB = (E + TILE - 1) / TILE;

    part_kernel<<<PB, 256, 0, stream>>>(src, dst, gcurD, gcurS, gbufD, gbufS, E, K);
    fillS_kernel<<<K, 256, 0, stream>>>(gcurS, gbufS, nsrc, N, K);
    fillD_kernel<<<K, 256, 0, stream>>>(gcurD, gbufD, csr_src, rowstart, indeg_i, ndst, N, K);

    gemm1_kernel<<<(N + 127) / 128, 256, 0, stream>>>(feat, W1, nsrc, (unsigned short*)h1, N);
    agg1_kernel<<<(N + 63) / 64, 256, 0, stream>>>(csr_src, rowstart, indeg_i, h1, ndst, nsrc, b1, x1s, N);
    agg2_kernel<<<(N + 63) / 64, 256, 0, stream>>>(csr_src, rowstart, indeg_i, x1s, ndst, a2, N);
    final_kernel<<<(N + 3) / 4, 256, 0, stream>>>(a2, W2, b2, out, N);
}